// Round 1
// baseline (19406.818 us; speedup 1.0000x reference)
//
#include <hip/hip_runtime.h>
#include <hip/hip_bf16.h>

#define N_ITEMS 100000
#define N_USERS 16384
#define HIST 50
#define K_ITEM 384   // TEXT_DIM + GCN_DIM
#define K_USER 256   // GCN_DIM + TOWER_DIM
#define HID 512
#define TOW 128

// Shared MLP micro-kernel: rows0..rows0+31 of  out = l2norm(relu(A@W1+b1)@W2+b2)
// A is a [32][K1] fp32 tile already staged in LDS. 256 threads.
// Thread (ty=tid>>5, tx=tid&31) owns a 4x4 micro-tile: rows ty*4..+3, cols tx*4..+3.
template<int K1>
__device__ __forceinline__ void mlp_tower(
    const float* __restrict__ Afeat,      // LDS [32][K1]
    float* __restrict__ Wt,               // LDS [32][128] scratch
    float* __restrict__ Hc,               // LDS [32][128] scratch
    const float* __restrict__ W1,         // [K1][512]
    const float* __restrict__ b1,         // [512]
    const float* __restrict__ W2,         // [512][128]
    const float* __restrict__ b2,         // [128]
    float* __restrict__ outp,             // [.][128], rows row0..row0+31
    int row0, int tid)
{
    const int tx = tid & 31;
    const int ty = tid >> 5;
    const float4* W1f4 = (const float4*)W1;
    const float4* W2f4 = (const float4*)W2;
    float4* Wtf4 = (float4*)Wt;
    float4* Hcf4 = (float4*)Hc;

    float4 acc2[4];
    #pragma unroll
    for (int r = 0; r < 4; ++r) acc2[r] = make_float4(0.f, 0.f, 0.f, 0.f);

    #pragma unroll
    for (int nc = 0; nc < 4; ++nc) {          // 4 chunks of 128 hidden cols
        float4 acc1[4];
        #pragma unroll
        for (int r = 0; r < 4; ++r) acc1[r] = make_float4(0.f, 0.f, 0.f, 0.f);

        for (int kc = 0; kc < K1 / 32; ++kc) {
            __syncthreads();   // prior Wt readers done
            #pragma unroll
            for (int j = 0; j < 4; ++j) {      // stage W1[kc*32..][nc*128..] tile
                int idx = tid + j * 256;
                int k = idx >> 5, n4 = idx & 31;
                Wtf4[k * 32 + n4] = W1f4[(kc * 32 + k) * (HID / 4) + nc * 32 + n4];
            }
            __syncthreads();
            #pragma unroll
            for (int k = 0; k < 32; ++k) {
                float4 w = Wtf4[k * 32 + tx];
                #pragma unroll
                for (int r = 0; r < 4; ++r) {
                    float a = Afeat[(ty * 4 + r) * K1 + kc * 32 + k];
                    acc1[r].x = fmaf(a, w.x, acc1[r].x);
                    acc1[r].y = fmaf(a, w.y, acc1[r].y);
                    acc1[r].z = fmaf(a, w.z, acc1[r].z);
                    acc1[r].w = fmaf(a, w.w, acc1[r].w);
                }
            }
        }
        // bias + relu -> Hc
        float4 bv = ((const float4*)b1)[nc * 32 + tx];
        __syncthreads();    // all Wt/Hc readers done
        #pragma unroll
        for (int r = 0; r < 4; ++r) {
            float4 h;
            h.x = fmaxf(acc1[r].x + bv.x, 0.f);
            h.y = fmaxf(acc1[r].y + bv.y, 0.f);
            h.z = fmaxf(acc1[r].z + bv.z, 0.f);
            h.w = fmaxf(acc1[r].w + bv.w, 0.f);
            Hcf4[(ty * 4 + r) * 32 + tx] = h;
        }
        __syncthreads();
        // partial layer 2: acc2 += Hc @ W2[nc*128 .. nc*128+128][:]
        #pragma unroll
        for (int kc2 = 0; kc2 < 4; ++kc2) {
            __syncthreads();
            #pragma unroll
            for (int j = 0; j < 4; ++j) {
                int idx = tid + j * 256;
                int k = idx >> 5, n4 = idx & 31;
                Wtf4[k * 32 + n4] = W2f4[(nc * 128 + kc2 * 32 + k) * (TOW / 4) + n4];
            }
            __syncthreads();
            #pragma unroll
            for (int k = 0; k < 32; ++k) {
                float4 w = Wtf4[k * 32 + tx];
                #pragma unroll
                for (int r = 0; r < 4; ++r) {
                    float a = Hc[(ty * 4 + r) * 128 + kc2 * 32 + k];
                    acc2[r].x = fmaf(a, w.x, acc2[r].x);
                    acc2[r].y = fmaf(a, w.y, acc2[r].y);
                    acc2[r].z = fmaf(a, w.z, acc2[r].z);
                    acc2[r].w = fmaf(a, w.w, acc2[r].w);
                }
            }
        }
    }
    // epilogue: +b2, l2norm per row, store
    float4 b2v = ((const float4*)b2)[tx];
    #pragma unroll
    for (int r = 0; r < 4; ++r) {
        float4 v;
        v.x = acc2[r].x + b2v.x;
        v.y = acc2[r].y + b2v.y;
        v.z = acc2[r].z + b2v.z;
        v.w = acc2[r].w + b2v.w;
        float s = v.x * v.x + v.y * v.y + v.z * v.z + v.w * v.w;
        #pragma unroll
        for (int m = 1; m <= 16; m <<= 1) s += __shfl_xor(s, m, 64);
        float inv = 1.0f / fmaxf(sqrtf(s), 1e-12f);
        v.x *= inv; v.y *= inv; v.z *= inv; v.w *= inv;
        ((float4*)outp)[(size_t)(row0 + ty * 4 + r) * 32 + tx] = v;
    }
}

__global__ __launch_bounds__(256, 2) void item_kernel(
    const float* __restrict__ text, const float* __restrict__ gcn,
    const float* __restrict__ W1, const float* __restrict__ b1,
    const float* __restrict__ W2, const float* __restrict__ b2,
    float* __restrict__ item_emb)
{
    __shared__ __align__(16) float Afeat[32 * K_ITEM];  // 48 KB
    __shared__ __align__(16) float Wt[32 * 128];        // 16 KB
    __shared__ __align__(16) float Hc[32 * 128];        // 16 KB
    const int tid = threadIdx.x;
    const int row0 = blockIdx.x * 32;
    float4* Af4 = (float4*)Afeat;
    const float4* tf4 = (const float4*)text;
    const float4* gf4 = (const float4*)gcn;
    // stage concat(text, gcn) rows: Afeat[r][0:256]=text, [256:384]=gcn
    #pragma unroll
    for (int j = 0; j < 8; ++j) {
        int idx = tid + j * 256;
        int r = idx >> 6, c4 = idx & 63;
        Af4[r * 96 + c4] = tf4[(size_t)(row0 + r) * 64 + c4];
    }
    #pragma unroll
    for (int j = 0; j < 4; ++j) {
        int idx = tid + j * 256;
        int r = idx >> 5, c4 = idx & 31;
        Af4[r * 96 + 64 + c4] = gf4[(size_t)(row0 + r) * 32 + c4];
    }
    __syncthreads();
    mlp_tower<K_ITEM>(Afeat, Wt, Hc, W1, b1, W2, b2, item_emb, row0, tid);
}

__global__ __launch_bounds__(256, 2) void user_kernel(
    const float* __restrict__ gcn_user, const int* __restrict__ hist,
    const float* __restrict__ item_emb,
    const float* __restrict__ W1, const float* __restrict__ b1,
    const float* __restrict__ W2, const float* __restrict__ b2,
    float* __restrict__ outp)
{
    __shared__ __align__(16) float Afeat[32 * K_USER];  // 32 KB
    __shared__ __align__(16) float Wt[32 * 128];
    __shared__ __align__(16) float Hc[32 * 128];
    const int tid = threadIdx.x;
    const int u0 = blockIdx.x * 32;
    const int u = tid >> 3;        // 0..31 user within tile
    const int g = tid & 7;         // 8 threads per user, 16 cols each
    float4* Af4 = (float4*)Afeat;
    const float4* ef4 = (const float4*)item_emb;
    const float4* gu4 = (const float4*)gcn_user;
    // left half: gcn_user
    #pragma unroll
    for (int j = 0; j < 4; ++j)
        Af4[u * 64 + g + 8 * j] = gu4[(u0 + u) * 32 + g + 8 * j];
    // right half: mean of gathered item embeddings
    float4 acc[4];
    #pragma unroll
    for (int j = 0; j < 4; ++j) acc[j] = make_float4(0.f, 0.f, 0.f, 0.f);
    const int* hrow = hist + (u0 + u) * HIST;
    for (int t = 0; t < HIST; ++t) {
        int idx = hrow[t];
        #pragma unroll
        for (int j = 0; j < 4; ++j) {
            float4 e = ef4[(size_t)idx * 32 + g + 8 * j];
            acc[j].x += e.x; acc[j].y += e.y; acc[j].z += e.z; acc[j].w += e.w;
        }
    }
    const float sc = 1.0f / 50.0f;
    #pragma unroll
    for (int j = 0; j < 4; ++j) {
        float4 m = make_float4(acc[j].x * sc, acc[j].y * sc, acc[j].z * sc, acc[j].w * sc);
        Af4[u * 64 + 32 + g + 8 * j] = m;
    }
    __syncthreads();
    mlp_tower<K_USER>(Afeat, Wt, Hc, W1, b1, W2, b2, outp, u0, tid);
}

extern "C" void kernel_launch(void* const* d_in, const int* in_sizes, int n_in,
                              void* d_out, int out_size, void* d_ws, size_t ws_size,
                              hipStream_t stream) {
    const float* text = (const float*)d_in[0];   // [100000,256]
    const float* gcni = (const float*)d_in[1];   // [100000,128]
    const float* gcnu = (const float*)d_in[2];   // [16384,128]
    const int*   hist = (const int*)d_in[3];     // [16384,50]
    const float* W1i  = (const float*)d_in[4];   // [384,512]
    const float* b1i  = (const float*)d_in[5];   // [512]
    const float* W2i  = (const float*)d_in[6];   // [512,128]
    const float* b2i  = (const float*)d_in[7];   // [128]
    const float* W1u  = (const float*)d_in[8];   // [256,512]
    const float* b1u  = (const float*)d_in[9];   // [512]
    const float* W2u  = (const float*)d_in[10];  // [512,128]
    const float* b2u  = (const float*)d_in[11];  // [128]
    float* out = (float*)d_out;                  // [16384,128] fp32

    float* item_emb = (float*)d_ws;              // 100000*128*4 = 51.2 MB

    item_kernel<<<N_ITEMS / 32, 256, 0, stream>>>(text, gcni, W1i, b1i, W2i, b2i, item_emb);
    user_kernel<<<N_USERS / 32, 256, 0, stream>>>(gcnu, hist, item_emb, W1u, b1u, W2u, b2u, out);
}

// Round 2
// 349.382 us; speedup vs baseline: 55.5461x; 55.5461x over previous
//
#include <hip/hip_runtime.h>
#include <hip/hip_bf16.h>

#define HIST 50

typedef __bf16 bf8 __attribute__((ext_vector_type(8)));
typedef float  f4  __attribute__((ext_vector_type(4)));

__device__ __forceinline__ unsigned short f2bf(float x) {
    unsigned u = __builtin_bit_cast(unsigned, x);
    u += 0x7fffu + ((u >> 16) & 1u);          // RNE
    return (unsigned short)(u >> 16);
}
__device__ __forceinline__ float bf2f(unsigned b) {
    unsigned u = b << 16;
    return __builtin_bit_cast(float, u);
}

// ---------------------------------------------------------------------------
// Weight packer: fp32 [K][N] -> bf16 MFMA B-fragments.
// Frag unit (nt, ks, lane l): 8 bf16 = B[ks*32 + (l>>4)*8 + j][nt*16 + (l&15)]
// stored contiguously at frag index (nt*KS + ks)*64 + l  (16 B per lane).
// ---------------------------------------------------------------------------
__global__ void pack_weights(const float* __restrict__ W1i, const float* __restrict__ W2i,
                             const float* __restrict__ W1u, const float* __restrict__ W2u,
                             unsigned short* __restrict__ dstbase)
{
    int i = blockIdx.x * 256 + threadIdx.x;   // 57344 total
    const float* W; unsigned short* dst; int N, KS, loc;
    if (i < 24576)      { W = W1i; dst = dstbase;          N = 512; KS = 12; loc = i; }          // 384x512
    else if (i < 32768) { W = W2i; dst = dstbase + 196608; N = 128; KS = 16; loc = i - 24576; }  // 512x128
    else if (i < 49152) { W = W1u; dst = dstbase + 262144; N = 512; KS = 8;  loc = i - 32768; }  // 256x512
    else                { W = W2u; dst = dstbase + 393216; N = 128; KS = 16; loc = i - 49152; }  // 512x128
    int l = loc & 63, fi = loc >> 6;
    int ks = fi % KS, nt = fi / KS;
    int q = l >> 4, c = l & 15;
    const float* src = W + (size_t)(ks * 32 + q * 8) * N + nt * 16 + c;
    unsigned o[4];
    #pragma unroll
    for (int k = 0; k < 4; ++k) {
        unsigned lo = f2bf(src[(2 * k) * N]);
        unsigned hi = f2bf(src[(2 * k + 1) * N]);
        o[k] = lo | (hi << 16);
    }
    uint4 v; v.x = o[0]; v.y = o[1]; v.z = o[2]; v.w = o[3];
    ((uint4*)dst)[(size_t)(nt * KS + ks) * 64 + l] = v;
}

// ---------------------------------------------------------------------------
// Fused 2-layer MLP + l2norm for 32 rows. A (bf16) already staged in LDS.
// 256 threads = 4 waves. Layer1: wave w owns cols w*128..+128 (8 n-tiles),
// rows 0..31 (2 row-tiles). Layer2: wave w owns cols w*32..+32 (2 n-tiles).
// MFMA 16x16x32 bf16; A-frag m=l&15,k=q*8+j; B-frag n=l&15,k=q*8+j;
// D row=q*4+reg, col=l&15  (m89-verified layouts).
// ---------------------------------------------------------------------------
template<int KS1, int ASTR, bool OUT_BF16>
__device__ __forceinline__ void two_layer(
    const unsigned short* As, unsigned short* Hs,
    const float* b1s, const float* b2s, float* sumsq,
    const bf8* __restrict__ w1f, const bf8* __restrict__ w2f,
    void* __restrict__ outp, int row0, int tid)
{
    const int HSTR = 528;                   // 512 + 16 pad (bank stride 4)
    const int l = tid & 63, w = tid >> 6;
    const int q = l >> 4, c = l & 15;

    f4 acc1[2][8];
    #pragma unroll
    for (int i = 0; i < 2; ++i)
        #pragma unroll
        for (int j = 0; j < 8; ++j) acc1[i][j] = (f4)0.0f;

    const unsigned short* a0p = As + c * ASTR + q * 8;
    const unsigned short* a1p = As + (16 + c) * ASTR + q * 8;
    for (int ks = 0; ks < KS1; ++ks) {
        bf8 a0 = *(const bf8*)(a0p + ks * 32);
        bf8 a1 = *(const bf8*)(a1p + ks * 32);
        const bf8* wp = w1f + ((size_t)(w * 8) * KS1 + ks) * 64 + l;
        #pragma unroll
        for (int nt = 0; nt < 8; ++nt) {
            bf8 b = wp[(size_t)nt * KS1 * 64];
            acc1[0][nt] = __builtin_amdgcn_mfma_f32_16x16x32_bf16(a0, b, acc1[0][nt], 0, 0, 0);
            acc1[1][nt] = __builtin_amdgcn_mfma_f32_16x16x32_bf16(a1, b, acc1[1][nt], 0, 0, 0);
        }
    }
    // bias + relu -> Hs (bf16)
    #pragma unroll
    for (int nt = 0; nt < 8; ++nt) {
        int col = (w * 8 + nt) * 16 + c;
        float bias = b1s[col];
        #pragma unroll
        for (int rt = 0; rt < 2; ++rt)
            #pragma unroll
            for (int reg = 0; reg < 4; ++reg) {
                float h = fmaxf(acc1[rt][nt][reg] + bias, 0.0f);
                Hs[(rt * 16 + q * 4 + reg) * HSTR + col] = f2bf(h);
            }
    }
    __syncthreads();

    // layer 2: K = 512 (16 k-steps), N = 128
    f4 acc2[2][2];
    #pragma unroll
    for (int i = 0; i < 2; ++i)
        #pragma unroll
        for (int j = 0; j < 2; ++j) acc2[i][j] = (f4)0.0f;

    const unsigned short* h0p = Hs + c * HSTR + q * 8;
    const unsigned short* h1p = Hs + (16 + c) * HSTR + q * 8;
    for (int ks = 0; ks < 16; ++ks) {
        bf8 a0 = *(const bf8*)(h0p + ks * 32);
        bf8 a1 = *(const bf8*)(h1p + ks * 32);
        #pragma unroll
        for (int j = 0; j < 2; ++j) {
            bf8 b = w2f[(size_t)((w * 2 + j) * 16 + ks) * 64 + l];
            acc2[0][j] = __builtin_amdgcn_mfma_f32_16x16x32_bf16(a0, b, acc2[0][j], 0, 0, 0);
            acc2[1][j] = __builtin_amdgcn_mfma_f32_16x16x32_bf16(a1, b, acc2[1][j], 0, 0, 0);
        }
    }
    // bias, row-wise sumsq (shfl over the 16 lanes sharing a row, then LDS atomic)
    float v[2][2][4];
    #pragma unroll
    for (int rt = 0; rt < 2; ++rt)
        #pragma unroll
        for (int j = 0; j < 2; ++j)
            #pragma unroll
            for (int reg = 0; reg < 4; ++reg)
                v[rt][j][reg] = acc2[rt][j][reg] + b2s[(w * 2 + j) * 16 + c];
    #pragma unroll
    for (int rt = 0; rt < 2; ++rt)
        #pragma unroll
        for (int reg = 0; reg < 4; ++reg) {
            float s = v[rt][0][reg] * v[rt][0][reg] + v[rt][1][reg] * v[rt][1][reg];
            s += __shfl_xor(s, 1); s += __shfl_xor(s, 2);
            s += __shfl_xor(s, 4); s += __shfl_xor(s, 8);
            if (c == 0) atomicAdd(&sumsq[rt * 16 + q * 4 + reg], s);
        }
    __syncthreads();
    #pragma unroll
    for (int rt = 0; rt < 2; ++rt)
        #pragma unroll
        for (int reg = 0; reg < 4; ++reg) {
            int row = rt * 16 + q * 4 + reg;
            float inv = 1.0f / fmaxf(sqrtf(sumsq[row]), 1e-12f);
            #pragma unroll
            for (int j = 0; j < 2; ++j) {
                int col = (w * 2 + j) * 16 + c;
                float o = v[rt][j][reg] * inv;
                if (OUT_BF16)
                    ((unsigned short*)outp)[(size_t)(row0 + row) * 128 + col] = f2bf(o);
                else
                    ((float*)outp)[(size_t)(row0 + row) * 128 + col] = o;
            }
        }
}

__global__ __launch_bounds__(256, 2) void item_kernel(
    const float* __restrict__ text, const float* __restrict__ gcn,
    const bf8* __restrict__ w1f, const float* __restrict__ b1,
    const bf8* __restrict__ w2f, const float* __restrict__ b2,
    unsigned short* __restrict__ item_bf)
{
    __shared__ unsigned short As[32 * 392];   // K=384 + 8 pad
    __shared__ unsigned short Hs[32 * 528];
    __shared__ float b1s[512], b2s[128], sumsq[32];
    const int tid = threadIdx.x;
    const int row0 = blockIdx.x * 32;
    const float4* t4 = (const float4*)text;
    const float4* g4 = (const float4*)gcn;
    #pragma unroll
    for (int j = 0; j < 8; ++j) {             // text: 32 x 256
        int idx = tid + j * 256; int r = idx >> 6, c4 = idx & 63;
        float4 x = t4[(size_t)(row0 + r) * 64 + c4];
        ushort4 s; s.x = f2bf(x.x); s.y = f2bf(x.y); s.z = f2bf(x.z); s.w = f2bf(x.w);
        *(ushort4*)(As + r * 392 + c4 * 4) = s;
    }
    #pragma unroll
    for (int j = 0; j < 4; ++j) {             // gcn: 32 x 128
        int idx = tid + j * 256; int r = idx >> 5, c4 = idx & 31;
        float4 x = g4[(size_t)(row0 + r) * 32 + c4];
        ushort4 s; s.x = f2bf(x.x); s.y = f2bf(x.y); s.z = f2bf(x.z); s.w = f2bf(x.w);
        *(ushort4*)(As + r * 392 + 256 + c4 * 4) = s;
    }
    b1s[tid] = b1[tid]; b1s[tid + 256] = b1[tid + 256];
    if (tid < 128) b2s[tid] = b2[tid];
    if (tid < 32)  sumsq[tid] = 0.0f;
    __syncthreads();
    two_layer<12, 392, true>(As, Hs, b1s, b2s, sumsq, w1f, w2f, item_bf, row0, tid);
}

__global__ __launch_bounds__(256, 2) void user_kernel(
    const float* __restrict__ gcnu, const int* __restrict__ hist,
    const unsigned short* __restrict__ item_bf,
    const bf8* __restrict__ w1f, const float* __restrict__ b1,
    const bf8* __restrict__ w2f, const float* __restrict__ b2,
    float* __restrict__ outp)
{
    __shared__ unsigned short As[32 * 272];   // K=256 + 16 pad
    __shared__ unsigned short Hs[32 * 528];
    __shared__ float b1s[512], b2s[128], sumsq[32];
    const int tid = threadIdx.x;
    const int u0 = blockIdx.x * 32;
    const float4* g4 = (const float4*)gcnu;
    #pragma unroll
    for (int j = 0; j < 4; ++j) {             // gcn_user: 32 x 128 -> cols 0..127
        int idx = tid + j * 256; int r = idx >> 5, c4 = idx & 31;
        float4 x = g4[(size_t)(u0 + r) * 32 + c4];
        ushort4 s; s.x = f2bf(x.x); s.y = f2bf(x.y); s.z = f2bf(x.z); s.w = f2bf(x.w);
        *(ushort4*)(As + r * 272 + c4 * 4) = s;
    }
    // history gather + mean -> cols 128..255. 8 threads/user, 16 cols each.
    {
        const int u = tid >> 3, g = tid & 7;
        float f[16];
        #pragma unroll
        for (int k = 0; k < 16; ++k) f[k] = 0.0f;
        const int* hrow = hist + (size_t)(u0 + u) * HIST;
        #pragma unroll 4
        for (int t = 0; t < HIST; ++t) {
            int id = hrow[t];
            const uint4* p = (const uint4*)(item_bf + (size_t)id * 128 + g * 16);
            uint4 x0 = p[0], x1 = p[1];
            unsigned vs[8] = {x0.x, x0.y, x0.z, x0.w, x1.x, x1.y, x1.z, x1.w};
            #pragma unroll
            for (int k = 0; k < 8; ++k) {
                f[2 * k]     += bf2f(vs[k] & 0xffffu);
                f[2 * k + 1] += bf2f(vs[k] >> 16);
            }
        }
        unsigned o[8];
        #pragma unroll
        for (int k = 0; k < 8; ++k)
            o[k] = (unsigned)f2bf(f[2 * k] * 0.02f) | ((unsigned)f2bf(f[2 * k + 1] * 0.02f) << 16);
        uint4 s0; s0.x = o[0]; s0.y = o[1]; s0.z = o[2]; s0.w = o[3];
        uint4 s1; s1.x = o[4]; s1.y = o[5]; s1.z = o[6]; s1.w = o[7];
        *(uint4*)(As + u * 272 + 128 + g * 16) = s0;
        *(uint4*)(As + u * 272 + 128 + g * 16 + 8) = s1;
    }
    b1s[tid] = b1[tid]; b1s[tid + 256] = b1[tid + 256];
    if (tid < 128) b2s[tid] = b2[tid];
    if (tid < 32)  sumsq[tid] = 0.0f;
    __syncthreads();
    two_layer<8, 272, false>(As, Hs, b1s, b2s, sumsq, w1f, w2f, outp, u0, tid);
}

extern "C" void kernel_launch(void* const* d_in, const int* in_sizes, int n_in,
                              void* d_out, int out_size, void* d_ws, size_t ws_size,
                              hipStream_t stream) {
    const float* text = (const float*)d_in[0];   // [100000,256]
    const float* gcni = (const float*)d_in[1];   // [100000,128]
    const float* gcnu = (const float*)d_in[2];   // [16384,128]
    const int*   hist = (const int*)d_in[3];     // [16384,50]
    const float* W1i  = (const float*)d_in[4];   // [384,512]
    const float* b1i  = (const float*)d_in[5];
    const float* W2i  = (const float*)d_in[6];   // [512,128]
    const float* b2i  = (const float*)d_in[7];
    const float* W1u  = (const float*)d_in[8];   // [256,512]
    const float* b1u  = (const float*)d_in[9];
    const float* W2u  = (const float*)d_in[10];  // [512,128]
    const float* b2u  = (const float*)d_in[11];
    float* out = (float*)d_out;                  // [16384,128] fp32

    // ws layout: item_emb bf16 [100000*128] (25.6 MB), then packed weights (0.9 MB)
    unsigned short* itemb = (unsigned short*)d_ws;
    unsigned short* pw = itemb + 12800000;

    pack_weights<<<224, 256, 0, stream>>>(W1i, W2i, W1u, W2u, pw);
    item_kernel<<<100000 / 32, 256, 0, stream>>>(
        text, gcni, (const bf8*)pw, b1i, (const bf8*)(pw + 196608), b2i, itemb);
    user_kernel<<<16384 / 32, 256, 0, stream>>>(
        gcnu, hist, itemb, (const bf8*)(pw + 262144), b1u, (const bf8*)(pw + 393216), b2u, out);
}